// Round 2
// baseline (373.264 us; speedup 1.0000x reference)
//
#include <hip/hip_runtime.h>
#include <math.h>

#define N_CODES       1024
#define CODE_DIM      64
#define ROWS_PER_BLK  256
#define THREADS       256

// numpy pairwise_sum of fl32(a[c]^2), n=64, scalar-8 path (AVX512 build: SIMD
// gate n >= nlanes*8 = 128 fails, so the classic 8-accumulator code runs):
//   r[j] = a[j]^2 + a[j+8]^2 + ... + a[j+56]^2   (serial adds, NO fma)
//   res  = ((r0+r1)+(r2+r3)) + ((r4+r5)+(r6+r7))
__device__ __forceinline__ float np_sumsq64(const float* a) {
#pragma clang fp contract(off)
    float r[8];
    #pragma unroll
    for (int j = 0; j < 8; ++j) r[j] = a[j] * a[j];
    #pragma unroll
    for (int t = 1; t < 8; ++t) {
        #pragma unroll
        for (int j = 0; j < 8; ++j) {
            float p = a[t * 8 + j] * a[t * 8 + j];
            r[j] = r[j] + p;
        }
    }
    return ((r[0] + r[1]) + (r[2] + r[3])) + ((r[4] + r[5]) + (r[6] + r[7]));
}

__global__ __launch_bounds__(THREADS, 2) void vq_np_emul_kernel(
    const float* __restrict__ vec,   // [32][64][64][64]  (b, c, h, w)
    const float* __restrict__ cb,    // [1024][64]
    float* __restrict__ out)         // [32][64][64][64]  (b, h, w, c)
{
    __shared__ float Cs[N_CODES];        // ||w_k||^2, numpy-pairwise fp32
    __shared__ int   idxs[ROWS_PER_BLK];

    const int tid  = threadIdx.x;
    const int base = blockIdx.x * ROWS_PER_BLK;
    const int b    = base >> 12;         // 4096 rows (h*w) per batch image
    const int hw0  = base & 4095;

    // ---- ||w_k||^2 with the exact numpy summation tree ----
    #pragma unroll
    for (int j = 0; j < N_CODES / THREADS; ++j) {
        const int k = tid + j * THREADS;
        Cs[k] = np_sumsq64(cb + k * CODE_DIM);
    }

    // ---- load this thread's row (coalesced: fixed c, consecutive hw) ----
    float xr[CODE_DIM];
    const float* xin = vec + (size_t)b * 262144 + hw0 + tid;
    #pragma unroll
    for (int c = 0; c < CODE_DIM; ++c) xr[c] = xin[(size_t)c * 4096];

    // ---- S = ||x||^2 with the exact numpy summation tree ----
    const float S = np_sumsq64(xr);

    __syncthreads();

    // ---- scan codes: d_k = fl32(fl32(S - 2*G_k) + C_k),
    //      G_k = serial fp32 FMA chain over c (OpenBLAS sgemm accumulator) ----
    float m  = INFINITY;
    int   mi = 0;
    for (int k = 0; k < N_CODES; ++k) {
        const float* w = cb + k * CODE_DIM;   // wave-uniform address
        float dot = 0.f;
        #pragma unroll
        for (int c = 0; c < CODE_DIM; ++c)
            dot = __builtin_fmaf(xr[c], w[c], dot);
        const float r = S - 2.0f * dot;       // x2 exact; fused or not, identical
        const float t = r + Cs[k];            // absorbed at scale ~64, kept for fidelity
        if (t < m) { m = t; mi = k; }         // strict < == numpy first-index argmin
    }

    idxs[tid] = mi;
    __syncthreads();

    // ---- cooperative gather + coalesced float4 output write ----
    const int c4 = (tid & 15) << 2;   // 0,4,...,60
    const int r0 = tid >> 4;          // 0..15
    for (int r = r0; r < ROWS_PER_BLK; r += 16) {
        const int w = idxs[r];
        const float4 v = *(const float4*)(cb + (size_t)w * CODE_DIM + c4);
        *(float4*)(out + (size_t)(base + r) * CODE_DIM + c4) = v;
    }
}

extern "C" void kernel_launch(void* const* d_in, const int* in_sizes, int n_in,
                              void* d_out, int out_size, void* d_ws, size_t ws_size,
                              hipStream_t stream) {
    const float* vec = (const float*)d_in[0];   // 32*64*64*64 fp32
    const float* cb  = (const float*)d_in[1];   // 1024*64 fp32
    float* out = (float*)d_out;                 // 32*64*64*64 fp32

    const int n_rows = 32 * 64 * 64;            // 131072
    dim3 grid(n_rows / ROWS_PER_BLK);           // 512
    dim3 block(THREADS);                        // 256
    vq_np_emul_kernel<<<grid, block, 0, stream>>>(vec, cb, out);
}